// Round 2
// baseline (117.717 us; speedup 1.0000x reference)
//
#include <hip/hip_runtime.h>
#include <math.h>

#define NT     128
#define NB     16
#define NH     512
#define SEQ_L  1024
#define FFT_N  2048
#define RS     0.70710678118654752f
#define C16    0.92387953251128675f   // cos(pi/8)
#define S16    0.38268343236508977f   // sin(pi/8)

// float2 LDS, pad 1 float2 per 16: Q(x) = x + (x>>4) at float2 granularity.
// Same affine folds as the old re/im layout, but every access is one b64 DS op
// instead of two b32 ops -> halves DS issue count.
// Bank check (16-lane phases): s1 stride-1 -> banks 0..31; mid stride-17 ->
// 2t mod 32 all distinct; s2 -> {2r} u {16+2r} covers 32 banks. Conflict-free.
#define BUF2_SZ 2176   // Q(2047) = 2174

// K in stage-permuted, conv-lane-coalesced order: [h][pair*128 + t] float4.
__device__ __align__(16) float4 g_kf4[(size_t)NH * (FFT_N / 2)];
// Twiddle tables: g_tw1[(c-1)*128 + t] = W_2048^(c*t), c=1..15, t=0..127
//                 g_tw2[(c-1)*8   + r] = W_128^(c*r),  c=1..15, r=0..7
__device__ float2 g_tw1[15 * 128];
__device__ float2 g_tw2[15 * 8];

__device__ __forceinline__ float2 cmul(float2 a, float2 b) {
    return make_float2(a.x * b.x - a.y * b.y, a.x * b.y + a.y * b.x);
}
__device__ __forceinline__ float2 cmulj(float2 a, float2 b) {  // a * conj(b)
    return make_float2(a.x * b.x + a.y * b.y, a.y * b.x - a.x * b.y);
}
__device__ __forceinline__ float2 cadd(float2 a, float2 b) { return make_float2(a.x + b.x, a.y + b.y); }
__device__ __forceinline__ float2 csub(float2 a, float2 b) { return make_float2(a.x - b.x, a.y - b.y); }

// In-place DFT4, natural order. SIGN=-1 fwd, SIGN=+1 inverse.
template <int SIGN>
__device__ __forceinline__ void dft4(float2 x[4]) {
    float2 s0 = cadd(x[0], x[2]), s1 = csub(x[0], x[2]);
    float2 s2 = cadd(x[1], x[3]), s3 = csub(x[1], x[3]);
    x[0] = cadd(s0, s2);
    x[2] = csub(s0, s2);
    if (SIGN < 0) {
        x[1] = make_float2(s1.x + s3.y, s1.y - s3.x);  // s1 - i*s3
        x[3] = make_float2(s1.x - s3.y, s1.y + s3.x);  // s1 + i*s3
    } else {
        x[1] = make_float2(s1.x - s3.y, s1.y + s3.x);
        x[3] = make_float2(s1.x + s3.y, s1.y - s3.x);
    }
}

// In-place DFT8, natural order (verified R4-R6).
template <int SIGN>
__device__ __forceinline__ void dft8(float2 x[8]) {
    float2 e0 = cadd(x[0], x[4]), e1 = cadd(x[1], x[5]);
    float2 e2 = cadd(x[2], x[6]), e3 = cadd(x[3], x[7]);
    float2 o0 = csub(x[0], x[4]), o1 = csub(x[1], x[5]);
    float2 o2 = csub(x[2], x[6]), o3 = csub(x[3], x[7]);
    float2 t1, t2, t3;
    if (SIGN < 0) {
        t1 = make_float2(RS * (o1.x + o1.y), RS * (o1.y - o1.x));
        t2 = make_float2(o2.y, -o2.x);
        t3 = make_float2(-RS * (o3.x - o3.y), -RS * (o3.x + o3.y));
    } else {
        t1 = make_float2(RS * (o1.x - o1.y), RS * (o1.x + o1.y));
        t2 = make_float2(-o2.y, o2.x);
        t3 = make_float2(RS * (-o3.x - o3.y), RS * (o3.x - o3.y));
    }
    float2 s0 = cadd(e0, e2), s1 = csub(e0, e2), s2 = cadd(e1, e3), s3 = csub(e1, e3);
    x[0] = cadd(s0, s2);
    x[4] = csub(s0, s2);
    float2 u0 = cadd(o0, t2), u1 = csub(o0, t2), u2 = cadd(t1, t3), u3 = csub(t1, t3);
    x[1] = cadd(u0, u2);
    x[5] = csub(u0, u2);
    if (SIGN < 0) {
        x[2] = make_float2(s1.x + s3.y, s1.y - s3.x);
        x[6] = make_float2(s1.x - s3.y, s1.y + s3.x);
        x[3] = make_float2(u1.x + u3.y, u1.y - u3.x);
        x[7] = make_float2(u1.x - u3.y, u1.y + u3.x);
    } else {
        x[2] = make_float2(s1.x - s3.y, s1.y + s3.x);
        x[6] = make_float2(s1.x + s3.y, s1.y - s3.x);
        x[3] = make_float2(u1.x - u3.y, u1.y + u3.x);
        x[7] = make_float2(u1.x + u3.y, u1.y - u3.x);
    }
}

// Internal W16 twiddles for the 4x4 CT decomposition of DFT16.
template <int SIGN>
__device__ __forceinline__ void dft16_twiddle(float2 v[4][4]) {
    const float sg = (SIGN < 0) ? -1.f : 1.f;
    const float2 W1 = make_float2(C16, sg * S16);
    const float2 W2 = make_float2(RS, sg * RS);
    const float2 W3 = make_float2(S16, sg * C16);
    const float2 W6 = make_float2(-RS, sg * RS);
    const float2 W9 = make_float2(-C16, -sg * S16);
    v[1][1] = cmul(v[1][1], W1);
    v[1][2] = cmul(v[1][2], W2);
    v[1][3] = cmul(v[1][3], W3);
    v[2][1] = cmul(v[2][1], W2);
    v[2][2] = make_float2(-sg * v[2][2].y, sg * v[2][2].x);  // *W16^4
    v[2][3] = cmul(v[2][3], W6);
    v[3][1] = cmul(v[3][1], W3);
    v[3][2] = cmul(v[3][2], W6);
    v[3][3] = cmul(v[3][3], W9);
}

// Full in-place DFT16, natural order.
template <int SIGN>
__device__ __forceinline__ void dft16(float2 x[16]) {
    float2 v[4][4];
#pragma unroll
    for (int n0 = 0; n0 < 4; ++n0) {
        float2 a[4] = {x[n0], x[n0 + 4], x[n0 + 8], x[n0 + 12]};
        dft4<SIGN>(a);
        v[n0][0] = a[0]; v[n0][1] = a[1]; v[n0][2] = a[2]; v[n0][3] = a[3];
    }
    dft16_twiddle<SIGN>(v);
#pragma unroll
    for (int k0 = 0; k0 < 4; ++k0) {
        float2 a[4] = {v[0][k0], v[1][k0], v[2][k0], v[3][k0]};
        dft4<SIGN>(a);
        x[k0] = a[0]; x[k0 + 4] = a[1]; x[k0 + 8] = a[2]; x[k0 + 12] = a[3];
    }
}

// Forward DFT16 with inputs 8..15 implicitly zero.
__device__ __forceinline__ void dft16_zero8(const float2 z[8], float2 x[16]) {
    float2 v[4][4];
#pragma unroll
    for (int n0 = 0; n0 < 4; ++n0) {
        float2 a = z[n0], b = z[n0 + 4];
        v[n0][0] = cadd(a, b);
        v[n0][1] = make_float2(a.x + b.y, a.y - b.x);   // a - i*b
        v[n0][2] = csub(a, b);
        v[n0][3] = make_float2(a.x - b.y, a.y + b.x);   // a + i*b
    }
    dft16_twiddle<-1>(v);
#pragma unroll
    for (int k0 = 0; k0 < 4; ++k0) {
        float2 a[4] = {v[0][k0], v[1][k0], v[2][k0], v[3][k0]};
        dft4<-1>(a);
        x[k0] = a[0]; x[k0 + 4] = a[1]; x[k0 + 8] = a[2]; x[k0 + 12] = a[3];
    }
}

// Inverse DFT16 computing only outputs 0..7.
__device__ __forceinline__ void dft16_inv_low8(const float2 x[16], float2 y[8]) {
    float2 v[4][4];
#pragma unroll
    for (int n0 = 0; n0 < 4; ++n0) {
        float2 a[4] = {x[n0], x[n0 + 4], x[n0 + 8], x[n0 + 12]};
        dft4<+1>(a);
        v[n0][0] = a[0]; v[n0][1] = a[1]; v[n0][2] = a[2]; v[n0][3] = a[3];
    }
    dft16_twiddle<+1>(v);
#pragma unroll
    for (int k0 = 0; k0 < 4; ++k0) {
        float2 x0 = v[0][k0], x1 = v[1][k0], x2 = v[2][k0], x3 = v[3][k0];
        float2 s0 = cadd(x0, x2), s1 = csub(x0, x2);
        float2 s2 = cadd(x1, x3), s3 = csub(x1, x3);
        y[k0]     = cadd(s0, s2);                             // k1 = 0
        y[k0 + 4] = make_float2(s1.x - s3.y, s1.y + s3.x);    // k1 = 1
    }
}

// Apply x[c] *= a^c (CONJ=0) or conj — power-tree version, used only in kfft.
template <int CONJ>
__device__ __forceinline__ void tw_apply16(float2 x[16], float2 a) {
#define AP(v, w) (v) = CONJ ? cmulj((v), (w)) : cmul((v), (w))
    AP(x[1], a);
    float2 w2 = cmul(a, a);      AP(x[2], w2);
    float2 w3 = cmul(w2, a);     AP(x[3], w3);
    float2 w4 = cmul(w2, w2);    AP(x[4], w4);
    float2 w5 = cmul(w4, a);     AP(x[5], w5);
    float2 w6 = cmul(w4, w2);    AP(x[6], w6);
    float2 w7 = cmul(w6, a);     AP(x[7], w7);
    float2 w8 = cmul(w4, w4);    AP(x[8], w8);
    float2 w9 = cmul(w8, a);     AP(x[9], w9);
    float2 w10 = cmul(w8, w2);   AP(x[10], w10);
    float2 w11 = cmul(w10, a);   AP(x[11], w11);
    float2 w12 = cmul(w8, w4);   AP(x[12], w12);
    float2 w13 = cmul(w12, a);   AP(x[13], w13);
    float2 w14 = cmul(w12, w2);  AP(x[14], w14);
    float2 w15 = cmul(w14, a);   AP(x[15], w15);
#undef AP
}

// ---- Kernel 1: K = fwd-chain(pad(k[h])) stored permuted+coalesced; also
// ---- builds the conv twiddle tables (spare work, blocks 0..15). ----
__global__ __launch_bounds__(NT, 2) void kfft_kernel(const float* __restrict__ kin) {
    __shared__ float2 buf[BUF2_SZ];
    __shared__ float2 twlds[NT];
    const int t = threadIdx.x;
    const int h = blockIdx.x;
    // --- twiddle-table build for conv (independent of this block's FFT) ---
    {
        const int gid = h * NT + t;
        if (gid < 15 * 128) {
            const int c = (gid >> 7) + 1, tt = gid & 127;
            float sv, cv;
            sincosf(-6.283185307179586f * (float)(c * tt) / (float)FFT_N, &sv, &cv);
            g_tw1[gid] = make_float2(cv, sv);
        } else if (gid < 15 * 128 + 15 * 8) {
            const int i2 = gid - 15 * 128;
            const int c = (i2 >> 3) + 1, r = i2 & 7;
            float sv, cv;
            sincosf(-6.283185307179586f * (float)(c * r) / 128.f, &sv, &cv);
            g_tw2[i2] = make_float2(cv, sv);
        }
    }
    float2 w1;
    {
        float sv, cv;
        sincosf(-6.283185307179586f * (float)t / (float)FFT_N, &sv, &cv);
        w1 = make_float2(cv, sv);
        twlds[t] = w1;
    }
    const int pb1 = t + (t >> 4);          // Q(t + 128c) = pb1 + 136c
    const float* krow = kin + (size_t)h * SEQ_L;
    {
        float2 z[8], x[16];
#pragma unroll
        for (int j = 0; j < 8; ++j) z[j] = make_float2(krow[t + 128 * j], 0.f);
        dft16_zero8(z, x);
        tw_apply16<0>(x, w1);
#pragma unroll
        for (int c = 0; c < 16; ++c) buf[pb1 + 136 * c] = x[c];
    }
    __syncthreads();
    const int cblk = t >> 3, r = t & 7;
    const int pb2 = 136 * cblk + r;        // Q(128cblk + r + 8j) = pb2 + 8j + (j>>1)
    {
        float2 x[16];
#pragma unroll
        for (int j = 0; j < 16; ++j) x[j] = buf[pb2 + 8 * j + (j >> 1)];
        dft16<-1>(x);
        tw_apply16<0>(x, twlds[16 * r]);
#pragma unroll
        for (int c2 = 0; c2 < 16; ++c2) buf[pb2 + 8 * c2 + (c2 >> 1)] = x[c2];
    }
    __syncthreads();
    const int pb3 = 17 * t;                // Q(16t + 8gi + l) = pb3 + 8gi + l
    float4* kf4 = g_kf4 + (size_t)h * (FFT_N / 2);
#pragma unroll
    for (int gi = 0; gi < 2; ++gi) {
        float2 x[8];
#pragma unroll
        for (int l = 0; l < 8; ++l) x[l] = buf[pb3 + 8 * gi + l];
        dft8<-1>(x);
#pragma unroll
        for (int q = 0; q < 4; ++q)
            kf4[(4 * gi + q) * 128 + t] =
                make_float4(x[2 * q].x, x[2 * q].y, x[2 * q + 1].x, x[2 * q + 1].y);
    }
}

// ---- Kernel 2: rows (2bp,h),(2bp+1,h) packed: fwd chain -> *K -> adjoint ----
__global__ __launch_bounds__(NT, 3) void conv_pair_kernel(const float* __restrict__ u,
                                                          const float* __restrict__ D,
                                                          float* __restrict__ out) {
    __shared__ float2 buf[BUF2_SZ];
    const int t = threadIdx.x;
    const int h = blockIdx.x & (NH - 1);
    const int bp = blockIdx.x >> 9;
    const size_t row0 = (size_t)(2 * bp) * NH + h;
    const size_t row1 = row0 + NH;
    const float* u0 = u + row0 * SEQ_L;
    const float* u1 = u + row1 * SEQ_L;
    const int pb1 = t + (t >> 4);
    // s1 fwd (write-only into LDS); u loaded fresh, NOT kept live
    {
        float2 z[8], x[16];
#pragma unroll
        for (int j = 0; j < 8; ++j)
            z[j] = make_float2(u0[t + 128 * j], u1[t + 128 * j]);
        dft16_zero8(z, x);
#pragma unroll
        for (int c = 1; c < 16; ++c)
            x[c] = cmul(x[c], g_tw1[(c - 1) * 128 + t]);
#pragma unroll
        for (int c = 0; c < 16; ++c) buf[pb1 + 136 * c] = x[c];
    }
    __syncthreads();
    // s2 fwd (in-place)
    const int cblk = t >> 3, r = t & 7;
    const int pb2 = 136 * cblk + r;
    {
        float2 x[16];
#pragma unroll
        for (int j = 0; j < 16; ++j) x[j] = buf[pb2 + 8 * j + (j >> 1)];
        dft16<-1>(x);
#pragma unroll
        for (int c = 1; c < 16; ++c)
            x[c] = cmul(x[c], g_tw2[(c - 1) * 8 + r]);
#pragma unroll
        for (int c2 = 0; c2 < 16; ++c2) buf[pb2 + 8 * c2 + (c2 >> 1)] = x[c2];
    }
    __syncthreads();
    // mid: dft8 fwd + elementwise *K + dft8 inv, all in registers
    {
        const float4* kf4 = g_kf4 + (size_t)h * (FFT_N / 2);
        const int pb3 = 17 * t;
#pragma unroll
        for (int gi = 0; gi < 2; ++gi) {
            float2 x[8];
#pragma unroll
            for (int l = 0; l < 8; ++l) x[l] = buf[pb3 + 8 * gi + l];
            dft8<-1>(x);
#pragma unroll
            for (int q = 0; q < 4; ++q) {
                float4 kk = kf4[(4 * gi + q) * 128 + t];
                x[2 * q]     = cmul(x[2 * q],     make_float2(kk.x, kk.y));
                x[2 * q + 1] = cmul(x[2 * q + 1], make_float2(kk.z, kk.w));
            }
            dft8<+1>(x);
#pragma unroll
            for (int l = 0; l < 8; ++l) buf[pb3 + 8 * gi + l] = x[l];
        }
    }
    __syncthreads();
    // prefetch epilogue u values (L1/L2-hot) so they're in flight over inv s2
    float up0[8], up1[8];
#pragma unroll
    for (int j = 0; j < 8; ++j) {
        up0[j] = u0[t + 128 * j];
        up1[j] = u1[t + 128 * j];
    }
    // inv s2 (adjoint: conj twiddle, then inverse butterfly; in-place)
    {
        float2 x[16];
#pragma unroll
        for (int c2 = 0; c2 < 16; ++c2) x[c2] = buf[pb2 + 8 * c2 + (c2 >> 1)];
#pragma unroll
        for (int c = 1; c < 16; ++c)
            x[c] = cmulj(x[c], g_tw2[(c - 1) * 8 + r]);
        dft16<+1>(x);
#pragma unroll
        for (int j = 0; j < 16; ++j) buf[pb2 + 8 * j + (j >> 1)] = x[j];
    }
    __syncthreads();
    // inv s1 + epilogue (only low 8 outputs needed)
    {
        float2 x[16];
#pragma unroll
        for (int c = 0; c < 16; ++c) x[c] = buf[pb1 + 136 * c];
#pragma unroll
        for (int c = 1; c < 16; ++c)
            x[c] = cmulj(x[c], g_tw1[(c - 1) * 128 + t]);
        float2 y[8];
        dft16_inv_low8(x, y);
        const float Dh = D[h];
        const float invN = 1.0f / (float)FFT_N;
        float* o0row = out + row0 * SEQ_L;
        float* o1row = out + row1 * SEQ_L;
#pragma unroll
        for (int j = 0; j < 8; ++j) {
            o0row[t + 128 * j] = y[j].x * invN + up0[j] * Dh;
            o1row[t + 128 * j] = y[j].y * invN + up1[j] * Dh;
        }
    }
}

extern "C" void kernel_launch(void* const* d_in, const int* in_sizes, int n_in,
                              void* d_out, int out_size, void* d_ws, size_t ws_size,
                              hipStream_t stream) {
    const float* u = (const float*)d_in[0];
    const float* k = (const float*)d_in[1];
    const float* D = (const float*)d_in[2];
    float* out = (float*)d_out;

    kfft_kernel<<<NH, NT, 0, stream>>>(k);
    conv_pair_kernel<<<NB * NH / 2, NT, 0, stream>>>(u, D, out);
}

// Round 3
// 116.787 us; speedup vs baseline: 1.0080x; 1.0080x over previous
//
#include <hip/hip_runtime.h>
#include <math.h>

#define NT     128
#define NB     16
#define NH     512
#define SEQ_L  1024
#define FFT_N  2048
#define RS     0.70710678118654752f
#define C16    0.92387953251128675f   // cos(pi/8)
#define S16    0.38268343236508977f   // sin(pi/8)

// float2 LDS, pad 1 float2 per 16: Q(x) = x + (x>>4) at float2 granularity.
// Folded affine bases -> one base VGPR + compile-time immediate per DS op.
// Bank check (16-lane phases): s1 stride-136 same-offset -> lanes hit 2t mod 32
// style patterns, <=2-way aliasing everywhere (free per m136).
#define BUF2_SZ 2176   // Q(2047) = 2174

// K in stage-permuted, conv-lane-coalesced order: [h][(4*gi+q)*128 + t] float4.
__device__ __align__(16) float4 g_kf4[(size_t)NH * (FFT_N / 2)];

__device__ __forceinline__ float2 cmul(float2 a, float2 b) {
    return make_float2(a.x * b.x - a.y * b.y, a.x * b.y + a.y * b.x);
}
__device__ __forceinline__ float2 cmulj(float2 a, float2 b) {  // a * conj(b)
    return make_float2(a.x * b.x + a.y * b.y, a.y * b.x - a.x * b.y);
}
__device__ __forceinline__ float2 cadd(float2 a, float2 b) { return make_float2(a.x + b.x, a.y + b.y); }
__device__ __forceinline__ float2 csub(float2 a, float2 b) { return make_float2(a.x - b.x, a.y - b.y); }

// In-place DFT4, natural order. SIGN=-1 fwd, SIGN=+1 inverse.
template <int SIGN>
__device__ __forceinline__ void dft4(float2 x[4]) {
    float2 s0 = cadd(x[0], x[2]), s1 = csub(x[0], x[2]);
    float2 s2 = cadd(x[1], x[3]), s3 = csub(x[1], x[3]);
    x[0] = cadd(s0, s2);
    x[2] = csub(s0, s2);
    if (SIGN < 0) {
        x[1] = make_float2(s1.x + s3.y, s1.y - s3.x);  // s1 - i*s3
        x[3] = make_float2(s1.x - s3.y, s1.y + s3.x);  // s1 + i*s3
    } else {
        x[1] = make_float2(s1.x - s3.y, s1.y + s3.x);
        x[3] = make_float2(s1.x + s3.y, s1.y - s3.x);
    }
}

// In-place DFT8, natural order (verified R4-R6).
template <int SIGN>
__device__ __forceinline__ void dft8(float2 x[8]) {
    float2 e0 = cadd(x[0], x[4]), e1 = cadd(x[1], x[5]);
    float2 e2 = cadd(x[2], x[6]), e3 = cadd(x[3], x[7]);
    float2 o0 = csub(x[0], x[4]), o1 = csub(x[1], x[5]);
    float2 o2 = csub(x[2], x[6]), o3 = csub(x[3], x[7]);
    float2 t1, t2, t3;
    if (SIGN < 0) {
        t1 = make_float2(RS * (o1.x + o1.y), RS * (o1.y - o1.x));
        t2 = make_float2(o2.y, -o2.x);
        t3 = make_float2(-RS * (o3.x - o3.y), -RS * (o3.x + o3.y));
    } else {
        t1 = make_float2(RS * (o1.x - o1.y), RS * (o1.x + o1.y));
        t2 = make_float2(-o2.y, o2.x);
        t3 = make_float2(RS * (-o3.x - o3.y), RS * (o3.x - o3.y));
    }
    float2 s0 = cadd(e0, e2), s1 = csub(e0, e2), s2 = cadd(e1, e3), s3 = csub(e1, e3);
    x[0] = cadd(s0, s2);
    x[4] = csub(s0, s2);
    float2 u0 = cadd(o0, t2), u1 = csub(o0, t2), u2 = cadd(t1, t3), u3 = csub(t1, t3);
    x[1] = cadd(u0, u2);
    x[5] = csub(u0, u2);
    if (SIGN < 0) {
        x[2] = make_float2(s1.x + s3.y, s1.y - s3.x);
        x[6] = make_float2(s1.x - s3.y, s1.y + s3.x);
        x[3] = make_float2(u1.x + u3.y, u1.y - u3.x);
        x[7] = make_float2(u1.x - u3.y, u1.y + u3.x);
    } else {
        x[2] = make_float2(s1.x - s3.y, s1.y + s3.x);
        x[6] = make_float2(s1.x + s3.y, s1.y - s3.x);
        x[3] = make_float2(u1.x - u3.y, u1.y + u3.x);
        x[7] = make_float2(u1.x + u3.y, u1.y - u3.x);
    }
}

// Internal W16 twiddles for the 4x4 CT decomposition of DFT16.
template <int SIGN>
__device__ __forceinline__ void dft16_twiddle(float2 v[4][4]) {
    const float sg = (SIGN < 0) ? -1.f : 1.f;
    const float2 W1 = make_float2(C16, sg * S16);
    const float2 W2 = make_float2(RS, sg * RS);
    const float2 W3 = make_float2(S16, sg * C16);
    const float2 W6 = make_float2(-RS, sg * RS);
    const float2 W9 = make_float2(-C16, -sg * S16);
    v[1][1] = cmul(v[1][1], W1);
    v[1][2] = cmul(v[1][2], W2);
    v[1][3] = cmul(v[1][3], W3);
    v[2][1] = cmul(v[2][1], W2);
    v[2][2] = make_float2(-sg * v[2][2].y, sg * v[2][2].x);  // *W16^4
    v[2][3] = cmul(v[2][3], W6);
    v[3][1] = cmul(v[3][1], W3);
    v[3][2] = cmul(v[3][2], W6);
    v[3][3] = cmul(v[3][3], W9);
}

// Full in-place DFT16, natural order.
template <int SIGN>
__device__ __forceinline__ void dft16(float2 x[16]) {
    float2 v[4][4];
#pragma unroll
    for (int n0 = 0; n0 < 4; ++n0) {
        float2 a[4] = {x[n0], x[n0 + 4], x[n0 + 8], x[n0 + 12]};
        dft4<SIGN>(a);
        v[n0][0] = a[0]; v[n0][1] = a[1]; v[n0][2] = a[2]; v[n0][3] = a[3];
    }
    dft16_twiddle<SIGN>(v);
#pragma unroll
    for (int k0 = 0; k0 < 4; ++k0) {
        float2 a[4] = {v[0][k0], v[1][k0], v[2][k0], v[3][k0]};
        dft4<SIGN>(a);
        x[k0] = a[0]; x[k0 + 4] = a[1]; x[k0 + 8] = a[2]; x[k0 + 12] = a[3];
    }
}

// Forward DFT16 with inputs 8..15 implicitly zero.
__device__ __forceinline__ void dft16_zero8(const float2 z[8], float2 x[16]) {
    float2 v[4][4];
#pragma unroll
    for (int n0 = 0; n0 < 4; ++n0) {
        float2 a = z[n0], b = z[n0 + 4];
        v[n0][0] = cadd(a, b);
        v[n0][1] = make_float2(a.x + b.y, a.y - b.x);   // a - i*b
        v[n0][2] = csub(a, b);
        v[n0][3] = make_float2(a.x - b.y, a.y + b.x);   // a + i*b
    }
    dft16_twiddle<-1>(v);
#pragma unroll
    for (int k0 = 0; k0 < 4; ++k0) {
        float2 a[4] = {v[0][k0], v[1][k0], v[2][k0], v[3][k0]};
        dft4<-1>(a);
        x[k0] = a[0]; x[k0 + 4] = a[1]; x[k0 + 8] = a[2]; x[k0 + 12] = a[3];
    }
}

// Inverse DFT16 computing only outputs 0..7.
__device__ __forceinline__ void dft16_inv_low8(const float2 x[16], float2 y[8]) {
    float2 v[4][4];
#pragma unroll
    for (int n0 = 0; n0 < 4; ++n0) {
        float2 a[4] = {x[n0], x[n0 + 4], x[n0 + 8], x[n0 + 12]};
        dft4<+1>(a);
        v[n0][0] = a[0]; v[n0][1] = a[1]; v[n0][2] = a[2]; v[n0][3] = a[3];
    }
    dft16_twiddle<+1>(v);
#pragma unroll
    for (int k0 = 0; k0 < 4; ++k0) {
        float2 x0 = v[0][k0], x1 = v[1][k0], x2 = v[2][k0], x3 = v[3][k0];
        float2 s0 = cadd(x0, x2), s1 = csub(x0, x2);
        float2 s2 = cadd(x1, x3), s3 = csub(x1, x3);
        y[k0]     = cadd(s0, s2);                             // k1 = 0
        y[k0 + 4] = make_float2(s1.x - s3.y, s1.y + s3.x);    // k1 = 1
    }
}

// Apply x[c] *= a^c (CONJ=0) or x[c] *= conj(a^c) (CONJ=1), c = 1..15.
// Log-depth power tree: pure VALU, zero memory latency (beats table loads
// at low occupancy — measured R0 vs R1/R2).
template <int CONJ>
__device__ __forceinline__ void tw_apply16(float2 x[16], float2 a) {
#define AP(v, w) (v) = CONJ ? cmulj((v), (w)) : cmul((v), (w))
    AP(x[1], a);
    float2 w2 = cmul(a, a);      AP(x[2], w2);
    float2 w3 = cmul(w2, a);     AP(x[3], w3);
    float2 w4 = cmul(w2, w2);    AP(x[4], w4);
    float2 w5 = cmul(w4, a);     AP(x[5], w5);
    float2 w6 = cmul(w4, w2);    AP(x[6], w6);
    float2 w7 = cmul(w6, a);     AP(x[7], w7);
    float2 w8 = cmul(w4, w4);    AP(x[8], w8);
    float2 w9 = cmul(w8, a);     AP(x[9], w9);
    float2 w10 = cmul(w8, w2);   AP(x[10], w10);
    float2 w11 = cmul(w10, a);   AP(x[11], w11);
    float2 w12 = cmul(w8, w4);   AP(x[12], w12);
    float2 w13 = cmul(w12, a);   AP(x[13], w13);
    float2 w14 = cmul(w12, w2);  AP(x[14], w14);
    float2 w15 = cmul(w14, a);   AP(x[15], w15);
#undef AP
}

// ---- Kernel 1: K = fwd-chain(pad(k[h])) stored permuted+coalesced ----
__global__ __launch_bounds__(NT, 2) void kfft_kernel(const float* __restrict__ kin) {
    __shared__ float2 buf[BUF2_SZ];
    __shared__ float2 twlds[NT];
    const int t = threadIdx.x;
    const int h = blockIdx.x;
    float2 w1;
    {
        float sv, cv;
        sincosf(-6.283185307179586f * (float)t / (float)FFT_N, &sv, &cv);
        w1 = make_float2(cv, sv);
        twlds[t] = w1;
    }
    const int pb1 = t + (t >> 4);          // Q(t + 128c) = pb1 + 136c
    const float* krow = kin + (size_t)h * SEQ_L;
    {
        float2 z[8], x[16];
#pragma unroll
        for (int j = 0; j < 8; ++j) z[j] = make_float2(krow[t + 128 * j], 0.f);
        dft16_zero8(z, x);
        tw_apply16<0>(x, w1);
#pragma unroll
        for (int c = 0; c < 16; ++c) buf[pb1 + 136 * c] = x[c];
    }
    __syncthreads();
    const int cblk = t >> 3, r = t & 7;
    const int pb2 = 136 * cblk + r;        // Q(128cblk + r + 8j) = pb2 + 8j + (j>>1)
    {
        float2 x[16];
#pragma unroll
        for (int j = 0; j < 16; ++j) x[j] = buf[pb2 + 8 * j + (j >> 1)];
        dft16<-1>(x);
        tw_apply16<0>(x, twlds[16 * r]);
#pragma unroll
        for (int c2 = 0; c2 < 16; ++c2) buf[pb2 + 8 * c2 + (c2 >> 1)] = x[c2];
    }
    __syncthreads();
    const int pb3 = 17 * t;                // Q(16t + 8gi + l) = pb3 + 8gi + l
    float4* kf4 = g_kf4 + (size_t)h * (FFT_N / 2);
#pragma unroll
    for (int gi = 0; gi < 2; ++gi) {
        float2 x[8];
#pragma unroll
        for (int l = 0; l < 8; ++l) x[l] = buf[pb3 + 8 * gi + l];
        dft8<-1>(x);
#pragma unroll
        for (int q = 0; q < 4; ++q)
            kf4[(4 * gi + q) * 128 + t] =
                make_float4(x[2 * q].x, x[2 * q].y, x[2 * q + 1].x, x[2 * q + 1].y);
    }
}

// ---- Kernel 2: rows (2bp,h),(2bp+1,h) packed: fwd chain -> *K -> adjoint ----
__global__ __launch_bounds__(NT, 2) void conv_pair_kernel(const float* __restrict__ u,
                                                          const float* __restrict__ D,
                                                          float* __restrict__ out) {
    __shared__ float2 buf[BUF2_SZ];
    __shared__ float2 twlds[NT];
    const int t = threadIdx.x;
    const int h = blockIdx.x & (NH - 1);
    const int bp = blockIdx.x >> 9;
    const size_t row0 = (size_t)(2 * bp) * NH + h;
    const size_t row1 = row0 + NH;
    const float* u0 = u + row0 * SEQ_L;
    const float* u1 = u + row1 * SEQ_L;
    float2 w1;
    {
        float sv, cv;
        sincosf(-6.283185307179586f * (float)t / (float)FFT_N, &sv, &cv);
        w1 = make_float2(cv, sv);
        twlds[t] = w1;
    }
    const int pb1 = t + (t >> 4);
    // s1 fwd (write-only into LDS); u loaded fresh, NOT kept live
    {
        float2 z[8], x[16];
#pragma unroll
        for (int j = 0; j < 8; ++j)
            z[j] = make_float2(u0[t + 128 * j], u1[t + 128 * j]);
        dft16_zero8(z, x);
        tw_apply16<0>(x, w1);
#pragma unroll
        for (int c = 0; c < 16; ++c) buf[pb1 + 136 * c] = x[c];
    }
    __syncthreads();
    // s2 fwd (in-place)
    const int cblk = t >> 3, r = t & 7;
    const int pb2 = 136 * cblk + r;
    const float2 ws = twlds[16 * r];   // W_128^r
    {
        float2 x[16];
#pragma unroll
        for (int j = 0; j < 16; ++j) x[j] = buf[pb2 + 8 * j + (j >> 1)];
        dft16<-1>(x);
        tw_apply16<0>(x, ws);
#pragma unroll
        for (int c2 = 0; c2 < 16; ++c2) buf[pb2 + 8 * c2 + (c2 >> 1)] = x[c2];
    }
    __syncthreads();
    // mid: dft8 fwd + elementwise *K + dft8 inv, all in registers
    {
        const float4* kf4 = g_kf4 + (size_t)h * (FFT_N / 2);
        const int pb3 = 17 * t;
#pragma unroll
        for (int gi = 0; gi < 2; ++gi) {
            float2 x[8];
#pragma unroll
            for (int l = 0; l < 8; ++l) x[l] = buf[pb3 + 8 * gi + l];
            dft8<-1>(x);
#pragma unroll
            for (int q = 0; q < 4; ++q) {
                float4 kk = kf4[(4 * gi + q) * 128 + t];
                x[2 * q]     = cmul(x[2 * q],     make_float2(kk.x, kk.y));
                x[2 * q + 1] = cmul(x[2 * q + 1], make_float2(kk.z, kk.w));
            }
            dft8<+1>(x);
#pragma unroll
            for (int l = 0; l < 8; ++l) buf[pb3 + 8 * gi + l] = x[l];
        }
    }
    __syncthreads();
    // prefetch epilogue u values (L1/L2-hot) so they're in flight over inv s2
    float up0[8], up1[8];
#pragma unroll
    for (int j = 0; j < 8; ++j) {
        up0[j] = u0[t + 128 * j];
        up1[j] = u1[t + 128 * j];
    }
    // inv s2 (adjoint: conj twiddle, then inverse butterfly; in-place)
    {
        float2 x[16];
#pragma unroll
        for (int c2 = 0; c2 < 16; ++c2) x[c2] = buf[pb2 + 8 * c2 + (c2 >> 1)];
        tw_apply16<1>(x, ws);
        dft16<+1>(x);
#pragma unroll
        for (int j = 0; j < 16; ++j) buf[pb2 + 8 * j + (j >> 1)] = x[j];
    }
    __syncthreads();
    // inv s1 + epilogue (only low 8 outputs needed)
    {
        float2 x[16];
#pragma unroll
        for (int c = 0; c < 16; ++c) x[c] = buf[pb1 + 136 * c];
        tw_apply16<1>(x, w1);
        float2 y[8];
        dft16_inv_low8(x, y);
        const float Dh = D[h];
        const float invN = 1.0f / (float)FFT_N;
        float* o0row = out + row0 * SEQ_L;
        float* o1row = out + row1 * SEQ_L;
#pragma unroll
        for (int j = 0; j < 8; ++j) {
            o0row[t + 128 * j] = y[j].x * invN + up0[j] * Dh;
            o1row[t + 128 * j] = y[j].y * invN + up1[j] * Dh;
        }
    }
}

extern "C" void kernel_launch(void* const* d_in, const int* in_sizes, int n_in,
                              void* d_out, int out_size, void* d_ws, size_t ws_size,
                              hipStream_t stream) {
    const float* u = (const float*)d_in[0];
    const float* k = (const float*)d_in[1];
    const float* D = (const float*)d_in[2];
    float* out = (float*)d_out;

    kfft_kernel<<<NH, NT, 0, stream>>>(k);
    conv_pair_kernel<<<NB * NH / 2, NT, 0, stream>>>(u, D, out);
}

// Round 4
// 110.894 us; speedup vs baseline: 1.0615x; 1.0531x over previous
//
#include <hip/hip_runtime.h>
#include <math.h>

#define NT     128
#define NB     16
#define NH     512
#define SEQ_L  1024
#define FFT_N  2048
#define RS     0.70710678118654752f
#define C16    0.92387953251128675f   // cos(pi/8)
#define S16    0.38268343236508977f   // sin(pi/8)

// Complex as a 2-wide fp32 ext-vector so the compiler emits packed VOP3P
// (v_pk_add_f32 / v_pk_mul_f32 / v_pk_fma_f32): 2 fp32 ops per instruction.
// All +-i twists are expressed as vector add of a (swap,neg) shuffle, which
// VOP3P encodes via op_sel + neg modifiers.
typedef float f2 __attribute__((ext_vector_type(2)));

__device__ __forceinline__ f2 in_(f2 v) { return (f2){v.y, -v.x}; }   // -i*v
__device__ __forceinline__ f2 ip_(f2 v) { return (f2){-v.y, v.x}; }   // +i*v
__device__ __forceinline__ f2 cmul(f2 a, f2 b) {                      // a*b
    return a.x * b + a.y * (f2){-b.y, b.x};
}
__device__ __forceinline__ f2 cmulj(f2 a, f2 b) {                     // a*conj(b)
    return b.x * a + b.y * (f2){a.y, -a.x};
}

// float2-granular padded LDS: Q(x) = x + (x>>4); folded affine bases ->
// one base VGPR + compile-time immediate per DS op; <=2-way bank aliasing
// everywhere (free, m136).
#define BUF2_SZ 2176   // Q(2047) = 2174

// K in stage-permuted, conv-lane-coalesced order: [h][(4*gi+q)*128 + t] float4.
__device__ __align__(16) float4 g_kf4[(size_t)NH * (FFT_N / 2)];

// In-place DFT4, natural order. SIGN=-1 fwd, SIGN=+1 inverse.
template <int SIGN>
__device__ __forceinline__ void dft4(f2 x[4]) {
    f2 s0 = x[0] + x[2], s1 = x[0] - x[2];
    f2 s2 = x[1] + x[3], s3 = x[1] - x[3];
    x[0] = s0 + s2;
    x[2] = s0 - s2;
    if (SIGN < 0) { x[1] = s1 + in_(s3); x[3] = s1 + ip_(s3); }
    else          { x[1] = s1 + ip_(s3); x[3] = s1 + in_(s3); }
}

// In-place DFT8, natural order.
template <int SIGN>
__device__ __forceinline__ void dft8(f2 x[8]) {
    f2 e0 = x[0] + x[4], e1 = x[1] + x[5];
    f2 e2 = x[2] + x[6], e3 = x[3] + x[7];
    f2 o0 = x[0] - x[4], o1 = x[1] - x[5];
    f2 o2 = x[2] - x[6], o3 = x[3] - x[7];
    f2 t1, t2, t3;
    if (SIGN < 0) {
        t1 = RS * (o1 + in_(o1));      // RS*(o1.x+o1.y, o1.y-o1.x)
        t2 = in_(o2);
        t3 = -RS * (o3 + ip_(o3));     // (-RS*(o3.x-o3.y), -RS*(o3.x+o3.y))
    } else {
        t1 = RS * (o1 + ip_(o1));
        t2 = ip_(o2);
        t3 = -RS * (o3 + in_(o3));
    }
    f2 s0 = e0 + e2, s1 = e0 - e2, s2 = e1 + e3, s3 = e1 - e3;
    x[0] = s0 + s2;
    x[4] = s0 - s2;
    f2 u0 = o0 + t2, u1 = o0 - t2, u2 = t1 + t3, u3 = t1 - t3;
    x[1] = u0 + u2;
    x[5] = u0 - u2;
    if (SIGN < 0) {
        x[2] = s1 + in_(s3); x[6] = s1 + ip_(s3);
        x[3] = u1 + in_(u3); x[7] = u1 + ip_(u3);
    } else {
        x[2] = s1 + ip_(s3); x[6] = s1 + in_(s3);
        x[3] = u1 + ip_(u3); x[7] = u1 + in_(u3);
    }
}

// Internal W16 twiddles for the 4x4 CT decomposition of DFT16.
template <int SIGN>
__device__ __forceinline__ void dft16_twiddle(f2 v[4][4]) {
    const float sg = (SIGN < 0) ? -1.f : 1.f;
    const f2 W1 = (f2){C16, sg * S16};
    const f2 W2 = (f2){RS, sg * RS};
    const f2 W3 = (f2){S16, sg * C16};
    const f2 W6 = (f2){-RS, sg * RS};
    const f2 W9 = (f2){-C16, -sg * S16};
    v[1][1] = cmul(v[1][1], W1);
    v[1][2] = cmul(v[1][2], W2);
    v[1][3] = cmul(v[1][3], W3);
    v[2][1] = cmul(v[2][1], W2);
    v[2][2] = (SIGN < 0) ? in_(v[2][2]) : ip_(v[2][2]);   // *W16^4
    v[2][3] = cmul(v[2][3], W6);
    v[3][1] = cmul(v[3][1], W3);
    v[3][2] = cmul(v[3][2], W6);
    v[3][3] = cmul(v[3][3], W9);
}

// Full in-place DFT16, natural order.
template <int SIGN>
__device__ __forceinline__ void dft16(f2 x[16]) {
    f2 v[4][4];
#pragma unroll
    for (int n0 = 0; n0 < 4; ++n0) {
        f2 a[4] = {x[n0], x[n0 + 4], x[n0 + 8], x[n0 + 12]};
        dft4<SIGN>(a);
        v[n0][0] = a[0]; v[n0][1] = a[1]; v[n0][2] = a[2]; v[n0][3] = a[3];
    }
    dft16_twiddle<SIGN>(v);
#pragma unroll
    for (int k0 = 0; k0 < 4; ++k0) {
        f2 a[4] = {v[0][k0], v[1][k0], v[2][k0], v[3][k0]};
        dft4<SIGN>(a);
        x[k0] = a[0]; x[k0 + 4] = a[1]; x[k0 + 8] = a[2]; x[k0 + 12] = a[3];
    }
}

// Forward DFT16 with inputs 8..15 implicitly zero.
__device__ __forceinline__ void dft16_zero8(const f2 z[8], f2 x[16]) {
    f2 v[4][4];
#pragma unroll
    for (int n0 = 0; n0 < 4; ++n0) {
        f2 a = z[n0], b = z[n0 + 4];
        v[n0][0] = a + b;
        v[n0][1] = a + in_(b);
        v[n0][2] = a - b;
        v[n0][3] = a + ip_(b);
    }
    dft16_twiddle<-1>(v);
#pragma unroll
    for (int k0 = 0; k0 < 4; ++k0) {
        f2 a[4] = {v[0][k0], v[1][k0], v[2][k0], v[3][k0]};
        dft4<-1>(a);
        x[k0] = a[0]; x[k0 + 4] = a[1]; x[k0 + 8] = a[2]; x[k0 + 12] = a[3];
    }
}

// Inverse DFT16 computing only outputs 0..7.
__device__ __forceinline__ void dft16_inv_low8(const f2 x[16], f2 y[8]) {
    f2 v[4][4];
#pragma unroll
    for (int n0 = 0; n0 < 4; ++n0) {
        f2 a[4] = {x[n0], x[n0 + 4], x[n0 + 8], x[n0 + 12]};
        dft4<+1>(a);
        v[n0][0] = a[0]; v[n0][1] = a[1]; v[n0][2] = a[2]; v[n0][3] = a[3];
    }
    dft16_twiddle<+1>(v);
#pragma unroll
    for (int k0 = 0; k0 < 4; ++k0) {
        f2 x0 = v[0][k0], x1 = v[1][k0], x2 = v[2][k0], x3 = v[3][k0];
        f2 s0 = x0 + x2, s1 = x0 - x2;
        f2 s2 = x1 + x3, s3 = x1 - x3;
        y[k0]     = s0 + s2;            // k1 = 0
        y[k0 + 4] = s1 + ip_(s3);       // k1 = 1
    }
}

// Apply x[c] *= a^c (CONJ=0) or x[c] *= conj(a^c) (CONJ=1), c = 1..15.
// Log-depth power tree: pure VALU, zero memory latency (beats table loads
// at low occupancy — measured R0 vs R1/R2).
template <int CONJ>
__device__ __forceinline__ void tw_apply16(f2 x[16], f2 a) {
#define AP(v, w) (v) = CONJ ? cmulj((v), (w)) : cmul((v), (w))
    AP(x[1], a);
    f2 w2 = cmul(a, a);      AP(x[2], w2);
    f2 w3 = cmul(w2, a);     AP(x[3], w3);
    f2 w4 = cmul(w2, w2);    AP(x[4], w4);
    f2 w5 = cmul(w4, a);     AP(x[5], w5);
    f2 w6 = cmul(w4, w2);    AP(x[6], w6);
    f2 w7 = cmul(w6, a);     AP(x[7], w7);
    f2 w8 = cmul(w4, w4);    AP(x[8], w8);
    f2 w9 = cmul(w8, a);     AP(x[9], w9);
    f2 w10 = cmul(w8, w2);   AP(x[10], w10);
    f2 w11 = cmul(w10, a);   AP(x[11], w11);
    f2 w12 = cmul(w8, w4);   AP(x[12], w12);
    f2 w13 = cmul(w12, a);   AP(x[13], w13);
    f2 w14 = cmul(w12, w2);  AP(x[14], w14);
    f2 w15 = cmul(w14, a);   AP(x[15], w15);
#undef AP
}

// ---- Kernel 1: K = fwd-chain(pad(k[h])) stored permuted+coalesced ----
__global__ __launch_bounds__(NT, 2) void kfft_kernel(const float* __restrict__ kin) {
    __shared__ f2 buf[BUF2_SZ];
    __shared__ f2 twlds[NT];
    const int t = threadIdx.x;
    const int h = blockIdx.x;
    f2 w1;
    {
        float sv, cv;
        sincosf(-6.283185307179586f * (float)t / (float)FFT_N, &sv, &cv);
        w1 = (f2){cv, sv};
        twlds[t] = w1;
    }
    const int pb1 = t + (t >> 4);          // Q(t + 128c) = pb1 + 136c
    const float* krow = kin + (size_t)h * SEQ_L;
    {
        f2 z[8], x[16];
#pragma unroll
        for (int j = 0; j < 8; ++j) z[j] = (f2){krow[t + 128 * j], 0.f};
        dft16_zero8(z, x);
        tw_apply16<0>(x, w1);
#pragma unroll
        for (int c = 0; c < 16; ++c) buf[pb1 + 136 * c] = x[c];
    }
    __syncthreads();
    const int cblk = t >> 3, r = t & 7;
    const int pb2 = 136 * cblk + r;        // Q(128cblk + r + 8j) = pb2 + 8j + (j>>1)
    {
        f2 x[16];
#pragma unroll
        for (int j = 0; j < 16; ++j) x[j] = buf[pb2 + 8 * j + (j >> 1)];
        dft16<-1>(x);
        tw_apply16<0>(x, twlds[16 * r]);
#pragma unroll
        for (int c2 = 0; c2 < 16; ++c2) buf[pb2 + 8 * c2 + (c2 >> 1)] = x[c2];
    }
    __syncthreads();
    const int pb3 = 17 * t;                // Q(16t + 8gi + l) = pb3 + 8gi + l
    float4* kf4 = g_kf4 + (size_t)h * (FFT_N / 2);
#pragma unroll
    for (int gi = 0; gi < 2; ++gi) {
        f2 x[8];
#pragma unroll
        for (int l = 0; l < 8; ++l) x[l] = buf[pb3 + 8 * gi + l];
        dft8<-1>(x);
#pragma unroll
        for (int q = 0; q < 4; ++q)
            kf4[(4 * gi + q) * 128 + t] =
                make_float4(x[2 * q].x, x[2 * q].y, x[2 * q + 1].x, x[2 * q + 1].y);
    }
}

// ---- Kernel 2: rows (2bp,h),(2bp+1,h) packed: fwd chain -> *K -> adjoint ----
__global__ __launch_bounds__(NT, 2) void conv_pair_kernel(const float* __restrict__ u,
                                                          const float* __restrict__ D,
                                                          float* __restrict__ out) {
    __shared__ f2 buf[BUF2_SZ];
    __shared__ f2 twlds[NT];
    const int t = threadIdx.x;
    const int h = blockIdx.x & (NH - 1);
    const int bp = blockIdx.x >> 9;
    const size_t row0 = (size_t)(2 * bp) * NH + h;
    const size_t row1 = row0 + NH;
    const float* u0 = u + row0 * SEQ_L;
    const float* u1 = u + row1 * SEQ_L;
    f2 w1;
    {
        float sv, cv;
        sincosf(-6.283185307179586f * (float)t / (float)FFT_N, &sv, &cv);
        w1 = (f2){cv, sv};
        twlds[t] = w1;
    }
    const int pb1 = t + (t >> 4);
    // s1 fwd (write-only into LDS); u loaded fresh, NOT kept live
    {
        f2 z[8], x[16];
#pragma unroll
        for (int j = 0; j < 8; ++j)
            z[j] = (f2){u0[t + 128 * j], u1[t + 128 * j]};
        dft16_zero8(z, x);
        tw_apply16<0>(x, w1);
#pragma unroll
        for (int c = 0; c < 16; ++c) buf[pb1 + 136 * c] = x[c];
    }
    __syncthreads();
    // s2 fwd (in-place)
    const int cblk = t >> 3, r = t & 7;
    const int pb2 = 136 * cblk + r;
    const f2 ws = twlds[16 * r];   // W_128^r
    {
        f2 x[16];
#pragma unroll
        for (int j = 0; j < 16; ++j) x[j] = buf[pb2 + 8 * j + (j >> 1)];
        dft16<-1>(x);
        tw_apply16<0>(x, ws);
#pragma unroll
        for (int c2 = 0; c2 < 16; ++c2) buf[pb2 + 8 * c2 + (c2 >> 1)] = x[c2];
    }
    __syncthreads();
    // mid: dft8 fwd + elementwise *K + dft8 inv, all in registers
    {
        const float4* kf4 = g_kf4 + (size_t)h * (FFT_N / 2);
        const int pb3 = 17 * t;
#pragma unroll
        for (int gi = 0; gi < 2; ++gi) {
            f2 x[8];
#pragma unroll
            for (int l = 0; l < 8; ++l) x[l] = buf[pb3 + 8 * gi + l];
            dft8<-1>(x);
#pragma unroll
            for (int q = 0; q < 4; ++q) {
                float4 kk = kf4[(4 * gi + q) * 128 + t];
                x[2 * q]     = cmul(x[2 * q],     (f2){kk.x, kk.y});
                x[2 * q + 1] = cmul(x[2 * q + 1], (f2){kk.z, kk.w});
            }
            dft8<+1>(x);
#pragma unroll
            for (int l = 0; l < 8; ++l) buf[pb3 + 8 * gi + l] = x[l];
        }
    }
    __syncthreads();
    // prefetch epilogue u values (L1/L2-hot) so they're in flight over inv s2
    float up0[8], up1[8];
#pragma unroll
    for (int j = 0; j < 8; ++j) {
        up0[j] = u0[t + 128 * j];
        up1[j] = u1[t + 128 * j];
    }
    // inv s2 (adjoint: conj twiddle, then inverse butterfly; in-place)
    {
        f2 x[16];
#pragma unroll
        for (int c2 = 0; c2 < 16; ++c2) x[c2] = buf[pb2 + 8 * c2 + (c2 >> 1)];
        tw_apply16<1>(x, ws);
        dft16<+1>(x);
#pragma unroll
        for (int j = 0; j < 16; ++j) buf[pb2 + 8 * j + (j >> 1)] = x[j];
    }
    __syncthreads();
    // inv s1 + epilogue (only low 8 outputs needed)
    {
        f2 x[16];
#pragma unroll
        for (int c = 0; c < 16; ++c) x[c] = buf[pb1 + 136 * c];
        tw_apply16<1>(x, w1);
        f2 y[8];
        dft16_inv_low8(x, y);
        const float Dh = D[h];
        const float invN = 1.0f / (float)FFT_N;
        float* o0row = out + row0 * SEQ_L;
        float* o1row = out + row1 * SEQ_L;
#pragma unroll
        for (int j = 0; j < 8; ++j) {
            o0row[t + 128 * j] = y[j].x * invN + up0[j] * Dh;
            o1row[t + 128 * j] = y[j].y * invN + up1[j] * Dh;
        }
    }
}

extern "C" void kernel_launch(void* const* d_in, const int* in_sizes, int n_in,
                              void* d_out, int out_size, void* d_ws, size_t ws_size,
                              hipStream_t stream) {
    const float* u = (const float*)d_in[0];
    const float* k = (const float*)d_in[1];
    const float* D = (const float*)d_in[2];
    float* out = (float*)d_out;

    kfft_kernel<<<NH, NT, 0, stream>>>(k);
    conv_pair_kernel<<<NB * NH / 2, NT, 0, stream>>>(u, D, out);
}